// Round 14
// baseline (96.594 us; speedup 1.0000x reference)
//
#include <hip/hip_runtime.h>

#define Bn 16
#define Qn 128
#define Kn 128
#define Dn 512
#define Hn 512
#define NEGV (-3.0e38f)
// 2*log2(e): exp2(PSCALE*x) == e^{2x}
#define PSCALE 2.8853900817779268f

typedef short s16x8 __attribute__((ext_vector_type(8)));
typedef float f32x4 __attribute__((ext_vector_type(4)));

__device__ __forceinline__ float exp2_hw(float x) {
  float r;
  asm("v_exp_f32 %0, %1" : "=v"(r) : "v"(x));
  return r;
}
__device__ __forceinline__ float rcp_hw(float x) { return __builtin_amdgcn_rcpf(x); }
__device__ __forceinline__ unsigned short f2bf(float f) {   // RNE f32->bf16
  unsigned int u = __float_as_uint(f);
  u += 0x7fff + ((u >> 16) & 1);
  return (unsigned short)(u >> 16);
}

// ---------- K1: W transpose + bf16: Wt[2][512 n][512 k] ----------
__global__ __launch_bounds__(256) void convert_w(
    const float* __restrict__ Wq, const float* __restrict__ Wk,
    unsigned short* __restrict__ Wt)
{
  const int tid = blockIdx.x * 256 + threadIdx.x;     // 0..32767
  const int n = tid & 511, rest = tid >> 9;           // rest 0..63
  const int sel = rest >> 5, k16 = rest & 31;
  const float* W = sel ? Wk : Wq;
  unsigned short o[16];
  #pragma unroll
  for (int i = 0; i < 16; ++i)
    o[i] = f2bf(W[(size_t)(k16 * 16 + i) * Hn + n]);
  unsigned short* dst = Wt + (size_t)sel * 262144 + (size_t)n * 512 + k16 * 16;
  #pragma unroll
  for (int j = 0; j < 4; ++j) *(ushort4*)(dst + j * 4) = *(ushort4*)&o[j * 4];
}

// ---------- K2: projections via bf16 MFMA, BM=64 BN=128 BK=64, grid (64,4) ----------
// q rows -> QW[q_glob][512 h][{WF,F}] f32 ; k rows -> Ekq[b][512 h][128 k] f32
__global__ __launch_bounds__(256) void proj_mfma(
    const float* __restrict__ queries, const float* __restrict__ keys,
    const unsigned short* __restrict__ Wt, const float* __restrict__ wv,
    float* __restrict__ QW, float* __restrict__ Ekq)
{
  __shared__ unsigned short Al[64][72];    // A tile (bf16)
  __shared__ unsigned short Bl[128][72];   // W tile (bf16)
  __shared__ float Tep[64][68];            // k-epilogue transpose chunk
  const int t = threadIdx.x, w = t >> 6, l = t & 63;
  const int wm = w >> 1, wn = w & 1;       // 2x2 waves: wm rows(32), wn cols(64)
  const int rowTile = blockIdx.x;          // 0..63 (64-row tiles)
  const int n0 = blockIdx.y * 128;
  const int R0 = rowTile * 64;
  const bool isQ = rowTile < 32;
  const float* Asrc = isQ ? queries : keys;
  const int rowBase = isQ ? R0 : (R0 - 2048);
  const unsigned short* Wsel = Wt + (isQ ? 0 : 262144);

  f32x4 acc[2][4];
  #pragma unroll
  for (int m = 0; m < 2; ++m)
    #pragma unroll
    for (int n = 0; n < 4; ++n) acc[m][n] = (f32x4)0.f;

  const int lr = l & 15, lk = l >> 4;

  for (int k0 = 0; k0 < Hn; k0 += 64) {
    float4 afr[4];
    ushort4 br[4][2];
    #pragma unroll
    for (int i = 0; i < 4; ++i) {          // A: 64r x 64k f32
      int g = t + 256 * i, r = g >> 4, c4 = g & 15;
      afr[i] = *(const float4*)(Asrc + (size_t)(rowBase + r) * Dn + k0 + c4 * 4);
    }
    #pragma unroll
    for (int i = 0; i < 4; ++i) {          // W: 128n x 64k bf16
      int g = t + 256 * i, r = g >> 3, c = g & 7;
      const unsigned short* p = Wsel + (size_t)(n0 + r) * Hn + k0 + c * 8;
      br[i][0] = *(const ushort4*)p; br[i][1] = *(const ushort4*)(p + 4);
    }
    __syncthreads();
    #pragma unroll
    for (int i = 0; i < 4; ++i) {
      int g = t + 256 * i, r = g >> 4, c4 = g & 15;
      ushort4 o = {f2bf(afr[i].x), f2bf(afr[i].y), f2bf(afr[i].z), f2bf(afr[i].w)};
      *(ushort4*)&Al[r][c4 * 4] = o;
    }
    #pragma unroll
    for (int i = 0; i < 4; ++i) {
      int g = t + 256 * i, r = g >> 3, c = g & 7;
      *(ushort4*)&Bl[r][c * 8] = br[i][0]; *(ushort4*)&Bl[r][c * 8 + 4] = br[i][1];
    }
    __syncthreads();
    #pragma unroll
    for (int ks = 0; ks < 2; ++ks) {
      s16x8 af[2], bf_[4];
      #pragma unroll
      for (int m = 0; m < 2; ++m)
        af[m] = *(const s16x8*)&Al[wm * 32 + m * 16 + lr][ks * 32 + lk * 8];
      #pragma unroll
      for (int n = 0; n < 4; ++n)
        bf_[n] = *(const s16x8*)&Bl[wn * 64 + n * 16 + lr][ks * 32 + lk * 8];
      #pragma unroll
      for (int m = 0; m < 2; ++m)
        #pragma unroll
        for (int n = 0; n < 4; ++n)
          acc[m][n] = __builtin_amdgcn_mfma_f32_16x16x32_bf16(af[m], bf_[n], acc[m][n], 0, 0, 0);
    }
    __syncthreads();
  }

  if (isQ) {
    #pragma unroll
    for (int m = 0; m < 2; ++m)
      #pragma unroll
      for (int n = 0; n < 4; ++n)
        #pragma unroll
        for (int r = 0; r < 4; ++r) {
          int row = R0 + wm * 32 + m * 16 + lk * 4 + r;
          int col = n0 + wn * 64 + n * 16 + lr;      // h
          float a = acc[m][n][r];
          float F  = exp2_hw(-PSCALE * a);           // e^{-2q}
          float WF = -2.f * wv[col] * F;
          float2 o = {WF, F};
          *(float2*)(QW + ((size_t)row * Hn + col) * 2) = o;
        }
  } else {
    const int krow0 = R0 - 2048;             // 0..1984, step 64
    const int bb = krow0 >> 7, kb = krow0 & 127;    // batch, k base (0|64)
    const int hl = t >> 2, kq = (t & 3) * 16;
    #pragma unroll
    for (int hc = 0; hc < 2; ++hc) {         // 64-h chunks; wave wn==hc writes
      __syncthreads();
      if (wn == hc) {
        #pragma unroll
        for (int m = 0; m < 2; ++m)
          #pragma unroll
          for (int n = 0; n < 4; ++n)
            #pragma unroll
            for (int r = 0; r < 4; ++r) {
              int row_l = wm * 32 + m * 16 + lk * 4 + r;   // k local 0..63
              int h_l = n * 16 + lr;                        // h local 0..63
              Tep[h_l][row_l] = exp2_hw(PSCALE * acc[m][n][r]);
            }
      }
      __syncthreads();
      float* dst = Ekq + (size_t)bb * 65536 + (size_t)(n0 + hc * 64 + hl) * 128 + kb + kq;
      #pragma unroll
      for (int j = 0; j < 4; ++j)
        *(float4*)(dst + j * 4) = *(const float4*)&Tep[hl][kq + j * 4];
    }
  }
}

// ---------- K3: score partials — DIAGNOSTIC x5 internal repeat ----------
// Identical math to R10; body repeated 5x (idempotent) to expose true cost
// in rocprof (dur/5) and wall clock (total = base + 4x score).
__global__ __launch_bounds__(256) void score_kernel(
    const float* __restrict__ QW, const float* __restrict__ Ekq,
    float* __restrict__ Sp)
{
  __shared__ float EkL[8192];              // [64 h][128 k] = 32KB
  __shared__ float QWL[32][132];           // 32 q x 128 (+4 pad)
  const int id = blockIdx.x;
  const int g = id & 127, qt = id >> 7;
  const int b = g >> 3, hs = g & 7;
  const int t = threadIdx.x, w = t >> 6, l = t & 63;
  const int qp = w * 8 + ((l >> 4) << 1);
  const int ka = (l & 15) * 4;
  const int h0 = hs * 64;

  for (int rep = 0; rep < 5; ++rep) {
    __syncthreads();                       // prev rep done reading LDS
    {
      const float4* esrc = (const float4*)(Ekq + (size_t)b * 65536 + (size_t)hs * 8192);
      float4 er[8];
      #pragma unroll
      for (int i = 0; i < 8; ++i) er[i] = esrc[t + 256 * i];
      const float* qsrc = QW + ((size_t)(b * Qn + qt * 32) * Hn + h0) * 2;
      const int qrow = t >> 3, qc = (t & 7) * 16;
      float4 qr4[4];
      #pragma unroll
      for (int i = 0; i < 4; ++i)
        qr4[i] = *(const float4*)(qsrc + (size_t)qrow * 1024 + qc + i * 4);
      float4* edst = (float4*)EkL;
      #pragma unroll
      for (int i = 0; i < 8; ++i) edst[t + 256 * i] = er[i];
      #pragma unroll
      for (int i = 0; i < 4; ++i)
        *(float4*)&QWL[qrow][qc + i * 4] = qr4[i];
    }
    __syncthreads();

    float acc0[8], acc1[8];
    #pragma unroll
    for (int j = 0; j < 8; ++j) { acc0[j] = 0.f; acc1[j] = 0.f; }

    #pragma unroll 4
    for (int hb = 0; hb < 32; ++hb) {
      const float* ekp = EkL + hb * 256;
      float4 ea0 = *(const float4*)(ekp + ka);
      float4 ea1 = *(const float4*)(ekp + 64 + ka);
      float4 eb0 = *(const float4*)(ekp + 128 + ka);
      float4 eb1 = *(const float4*)(ekp + 192 + ka);
      float4 qv0 = *(const float4*)&QWL[qp][hb * 4];
      float4 qv1 = *(const float4*)&QWL[qp + 1][hb * 4];
      {
        const float WF0 = qv0.x, F0 = qv0.y, WF1 = qv0.z, F1 = qv0.w;
        float d0, d1, num;
        d0 = F0 + ea0.x; d1 = F1 + eb0.x;
        num = __builtin_fmaf(WF0, d1, WF1 * d0);
        acc0[0] = __builtin_fmaf(num, rcp_hw(d0 * d1), acc0[0]);
        d0 = F0 + ea0.y; d1 = F1 + eb0.y;
        num = __builtin_fmaf(WF0, d1, WF1 * d0);
        acc0[1] = __builtin_fmaf(num, rcp_hw(d0 * d1), acc0[1]);
        d0 = F0 + ea0.z; d1 = F1 + eb0.z;
        num = __builtin_fmaf(WF0, d1, WF1 * d0);
        acc0[2] = __builtin_fmaf(num, rcp_hw(d0 * d1), acc0[2]);
        d0 = F0 + ea0.w; d1 = F1 + eb0.w;
        num = __builtin_fmaf(WF0, d1, WF1 * d0);
        acc0[3] = __builtin_fmaf(num, rcp_hw(d0 * d1), acc0[3]);
        d0 = F0 + ea1.x; d1 = F1 + eb1.x;
        num = __builtin_fmaf(WF0, d1, WF1 * d0);
        acc0[4] = __builtin_fmaf(num, rcp_hw(d0 * d1), acc0[4]);
        d0 = F0 + ea1.y; d1 = F1 + eb1.y;
        num = __builtin_fmaf(WF0, d1, WF1 * d0);
        acc0[5] = __builtin_fmaf(num, rcp_hw(d0 * d1), acc0[5]);
        d0 = F0 + ea1.z; d1 = F1 + eb1.z;
        num = __builtin_fmaf(WF0, d1, WF1 * d0);
        acc0[6] = __builtin_fmaf(num, rcp_hw(d0 * d1), acc0[6]);
        d0 = F0 + ea1.w; d1 = F1 + eb1.w;
        num = __builtin_fmaf(WF0, d1, WF1 * d0);
        acc0[7] = __builtin_fmaf(num, rcp_hw(d0 * d1), acc0[7]);
      }
      {
        const float WF0 = qv1.x, F0 = qv1.y, WF1 = qv1.z, F1 = qv1.w;
        float d0, d1, num;
        d0 = F0 + ea0.x; d1 = F1 + eb0.x;
        num = __builtin_fmaf(WF0, d1, WF1 * d0);
        acc1[0] = __builtin_fmaf(num, rcp_hw(d0 * d1), acc1[0]);
        d0 = F0 + ea0.y; d1 = F1 + eb0.y;
        num = __builtin_fmaf(WF0, d1, WF1 * d0);
        acc1[1] = __builtin_fmaf(num, rcp_hw(d0 * d1), acc1[1]);
        d0 = F0 + ea0.z; d1 = F1 + eb0.z;
        num = __builtin_fmaf(WF0, d1, WF1 * d0);
        acc1[2] = __builtin_fmaf(num, rcp_hw(d0 * d1), acc1[2]);
        d0 = F0 + ea0.w; d1 = F1 + eb0.w;
        num = __builtin_fmaf(WF0, d1, WF1 * d0);
        acc1[3] = __builtin_fmaf(num, rcp_hw(d0 * d1), acc1[3]);
        d0 = F0 + ea1.x; d1 = F1 + eb1.x;
        num = __builtin_fmaf(WF0, d1, WF1 * d0);
        acc1[4] = __builtin_fmaf(num, rcp_hw(d0 * d1), acc1[4]);
        d0 = F0 + ea1.y; d1 = F1 + eb1.y;
        num = __builtin_fmaf(WF0, d1, WF1 * d0);
        acc1[5] = __builtin_fmaf(num, rcp_hw(d0 * d1), acc1[5]);
        d0 = F0 + ea1.z; d1 = F1 + eb1.z;
        num = __builtin_fmaf(WF0, d1, WF1 * d0);
        acc1[6] = __builtin_fmaf(num, rcp_hw(d0 * d1), acc1[6]);
        d0 = F0 + ea1.w; d1 = F1 + eb1.w;
        num = __builtin_fmaf(WF0, d1, WF1 * d0);
        acc1[7] = __builtin_fmaf(num, rcp_hw(d0 * d1), acc1[7]);
      }
    }

    const int q = qt * 32 + qp;
    size_t sb = (((size_t)hs * Bn + b) * Qn + q) * Kn;
    *(float4*)(Sp + sb + ka)            = (float4){acc0[0], acc0[1], acc0[2], acc0[3]};
    *(float4*)(Sp + sb + 64 + ka)       = (float4){acc0[4], acc0[5], acc0[6], acc0[7]};
    *(float4*)(Sp + sb + Kn + ka)       = (float4){acc1[0], acc1[1], acc1[2], acc1[3]};
    *(float4*)(Sp + sb + Kn + 64 + ka)  = (float4){acc1[4], acc1[5], acc1[6], acc1[7]};
  }
}

// ---------- K4: sum 8 h-partials + masked softmax -> At bf16 ----------
__global__ __launch_bounds__(512) void softmax_kernel(
    const float* __restrict__ Sp, const int* __restrict__ valid_lens,
    unsigned short* __restrict__ At)
{
  const int t = threadIdx.x;
  const int b = blockIdx.y;
  const int q = blockIdx.x * 16 + (t >> 5);
  const int k0 = (t & 31) * 4;
  const size_t base = ((size_t)b * Qn + q) * Kn + k0;

  float s[4] = {0.f, 0.f, 0.f, 0.f};
  #pragma unroll
  for (int p = 0; p < 8; ++p) {
    float4 sv = *(const float4*)(Sp + base + (size_t)p * 262144);
    s[0] += sv.x; s[1] += sv.y; s[2] += sv.z; s[3] += sv.w;
  }

  const int vlen = valid_lens[b];
  bool ok[4];
  float m = NEGV;
  #pragma unroll
  for (int j = 0; j < 4; ++j) {
    ok[j] = (k0 + j) < vlen;
    if (ok[j]) m = fmaxf(m, s[j]);
  }
  #pragma unroll
  for (int xm = 16; xm >= 1; xm >>= 1) m = fmaxf(m, __shfl_xor(m, xm, 32));
  float e[4], sum = 0.f;
  #pragma unroll
  for (int j = 0; j < 4; ++j) {
    e[j] = ok[j] ? exp2_hw((s[j] - m) * 1.44269504f) : 0.f;
    sum += e[j];
  }
  #pragma unroll
  for (int xm = 16; xm >= 1; xm >>= 1) sum += __shfl_xor(sum, xm, 32);
  float inv = rcp_hw(sum);
  ushort4 o = {f2bf(e[0] * inv), f2bf(e[1] * inv), f2bf(e[2] * inv), f2bf(e[3] * inv)};
  *(ushort4*)(At + base) = o;
}

// ---------- K5: out = At @ V via bf16 MFMA, d-tile 64, grid (8,16) ----------
__global__ __launch_bounds__(256) void av_mfma(
    const unsigned short* __restrict__ At, const float* __restrict__ values,
    float* __restrict__ out)
{
  __shared__ unsigned short AtL[128][72];
  __shared__ unsigned short VL[64][72];
  const int t = threadIdx.x, w = t >> 6, l = t & 63;
  const int wm = w >> 1, wn = w & 1;       // wm: q(64), wn: d(32)
  const int dt = blockIdx.x;               // 0..7 (64-col d tiles)
  const int b = blockIdx.y;
  const int lr = l & 15, lk = l >> 4;

  f32x4 acc[4][2];
  #pragma unroll
  for (int m = 0; m < 4; ++m)
    #pragma unroll
    for (int n = 0; n < 2; ++n) acc[m][n] = (f32x4)0.f;

  const unsigned short* Atb = At + (size_t)b * Qn * Kn;

  for (int k0 = 0; k0 < Kn; k0 += 64) {
    ushort4 ar[4][2];
    float4 vv[4];
    #pragma unroll
    for (int i = 0; i < 4; ++i) {          // At: 128q x 64k bf16
      int g = t + 256 * i, r = g >> 3, c = g & 7;
      const unsigned short* p = Atb + (size_t)r * Kn + k0 + c * 8;
      ar[i][0] = *(const ushort4*)p; ar[i][1] = *(const ushort4*)(p + 4);
    }
    #pragma unroll
    for (int j = 0; j < 4; ++j) {          // V: 64k x 64d f32
      int idx = t + 256 * j, k_l = idx >> 4, d4 = idx & 15;
      vv[j] = *(const float4*)(values + ((size_t)(b * Kn) + k0 + k_l) * Dn + dt * 64 + d4 * 4);
    }
    __syncthreads();
    #pragma unroll
    for (int i = 0; i < 4; ++i) {
      int g = t + 256 * i, r = g >> 3, c = g & 7;
      *(ushort4*)&AtL[r][c * 8] = ar[i][0]; *(ushort4*)&AtL[r][c * 8 + 4] = ar[i][1];
    }
    #pragma unroll
    for (int j = 0; j < 4; ++j) {
      int idx = t + 256 * j, k_l = idx >> 4, d4 = idx & 15;
      VL[d4 * 4 + 0][k_l] = f2bf(vv[j].x);
      VL[d4 * 4 + 1][k_l] = f2bf(vv[j].y);
      VL[d4 * 4 + 2][k_l] = f2bf(vv[j].z);
      VL[d4 * 4 + 3][k_l] = f2bf(vv[j].w);
    }
    __syncthreads();
    #pragma unroll
    for (int ks = 0; ks < 2; ++ks) {
      s16x8 af[4], bf_[2];
      #pragma unroll
      for (int m = 0; m < 4; ++m)
        af[m] = *(const s16x8*)&AtL[wm * 64 + m * 16 + lr][ks * 32 + lk * 8];
      #pragma unroll
      for (int n = 0; n < 2; ++n)
        bf_[n] = *(const s16x8*)&VL[wn * 32 + n * 16 + lr][ks * 32 + lk * 8];
      #pragma unroll
      for (int m = 0; m < 4; ++m)
        #pragma unroll
        for (int n = 0; n < 2; ++n)
          acc[m][n] = __builtin_amdgcn_mfma_f32_16x16x32_bf16(af[m], bf_[n], acc[m][n], 0, 0, 0);
    }
    __syncthreads();
  }

  #pragma unroll
  for (int m = 0; m < 4; ++m)
    #pragma unroll
    for (int n = 0; n < 2; ++n)
      #pragma unroll
      for (int r = 0; r < 4; ++r) {
        int row = wm * 64 + m * 16 + lk * 4 + r;
        int col = dt * 64 + wn * 32 + n * 16 + lr;
        out[((size_t)(b * Qn) + row) * Dn + col] = acc[m][n][r];
      }
}

extern "C" void kernel_launch(void* const* d_in, const int* in_sizes, int n_in,
                              void* d_out, int out_size, void* d_ws, size_t ws_size,
                              hipStream_t stream) {
  const float* queries    = (const float*)d_in[0];
  const float* keys       = (const float*)d_in[1];
  const float* values     = (const float*)d_in[2];
  const int*   valid_lens = (const int*)d_in[3];
  const float* Wq         = (const float*)d_in[4];
  const float* Wk         = (const float*)d_in[5];
  const float* wv         = (const float*)d_in[6];
  float* out = (float*)d_out;

  unsigned short* Wt  = (unsigned short*)d_ws;     // 2*512*512 bf16      (1MB)
  float*          QW  = (float*)(Wt + 524288);     // 2048*512*2 f32      (8MB)
  float*          Ekq = QW + 2097152;              // 16*512*128 f32      (4MB)
  float*          Sp  = Ekq + 1048576;             // 8*16*128*128 f32    (8MB)
  unsigned short* At  = (unsigned short*)(Sp + 2097152); // 16*128*128    (0.5MB)

  convert_w<<<128, 256, 0, stream>>>(Wq, Wk, Wt);
  proj_mfma<<<dim3(64, 4), 256, 0, stream>>>(queries, keys, Wt, wv, QW, Ekq);
  score_kernel<<<512, 256, 0, stream>>>(QW, Ekq, Sp);
  softmax_kernel<<<dim3(8, 16), 512, 0, stream>>>(Sp, valid_lens, At);
  av_mfma<<<dim3(8, 16), 256, 0, stream>>>(At, values, out);
}

// Round 15
// 47.473 us; speedup vs baseline: 2.0347x; 2.0347x over previous
//
#include <hip/hip_runtime.h>

#define Bn 16
#define Qn 128
#define Kn 128
#define Dn 512
#define Hn 512
#define NEGV (-3.0e38f)
// 2*log2(e): exp2(PSCALE*x) == e^{2x}
#define PSCALE 2.8853900817779268f

typedef short s16x8 __attribute__((ext_vector_type(8)));
typedef float f32x4 __attribute__((ext_vector_type(4)));

__device__ __forceinline__ float exp2_hw(float x) {
  float r;
  asm("v_exp_f32 %0, %1" : "=v"(r) : "v"(x));
  return r;
}
__device__ __forceinline__ float rcp_hw(float x) { return __builtin_amdgcn_rcpf(x); }
__device__ __forceinline__ unsigned short f2bf(float f) {   // RNE f32->bf16
  unsigned int u = __float_as_uint(f);
  u += 0x7fff + ((u >> 16) & 1);
  return (unsigned short)(u >> 16);
}
__device__ __forceinline__ unsigned int pack2bf(float lo, float hi) {
  return (unsigned int)f2bf(lo) | ((unsigned int)f2bf(hi) << 16);
}

// ---------- K1: W transpose + bf16: Wt[2][512 n][512 k] ----------
__global__ __launch_bounds__(256) void convert_w(
    const float* __restrict__ Wq, const float* __restrict__ Wk,
    unsigned short* __restrict__ Wt)
{
  const int tid = blockIdx.x * 256 + threadIdx.x;     // 0..32767
  const int n = tid & 511, rest = tid >> 9;           // rest 0..63
  const int sel = rest >> 5, k16 = rest & 31;
  const float* W = sel ? Wk : Wq;
  unsigned short o[16];
  #pragma unroll
  for (int i = 0; i < 16; ++i)
    o[i] = f2bf(W[(size_t)(k16 * 16 + i) * Hn + n]);
  unsigned short* dst = Wt + (size_t)sel * 262144 + (size_t)n * 512 + k16 * 16;
  #pragma unroll
  for (int j = 0; j < 4; ++j) *(ushort4*)(dst + j * 4) = *(ushort4*)&o[j * 4];
}

// ---------- K2: projections via bf16 MFMA, BM=64 BN=128 BK=64, grid (64,4) ----------
// q rows -> QW[q_glob][512 h][{WF,F}] f32 ; k rows -> Ekq[b][512 h][128 k] f32
__global__ __launch_bounds__(256) void proj_mfma(
    const float* __restrict__ queries, const float* __restrict__ keys,
    const unsigned short* __restrict__ Wt, const float* __restrict__ wv,
    float* __restrict__ QW, float* __restrict__ Ekq)
{
  __shared__ unsigned short Al[64][72];    // A tile (bf16)
  __shared__ unsigned short Bl[128][72];   // W tile (bf16)
  __shared__ float Tep[64][68];            // k-epilogue transpose chunk
  const int t = threadIdx.x, w = t >> 6, l = t & 63;
  const int wm = w >> 1, wn = w & 1;       // 2x2 waves: wm rows(32), wn cols(64)
  const int rowTile = blockIdx.x;          // 0..63 (64-row tiles)
  const int n0 = blockIdx.y * 128;
  const int R0 = rowTile * 64;
  const bool isQ = rowTile < 32;
  const float* Asrc = isQ ? queries : keys;
  const int rowBase = isQ ? R0 : (R0 - 2048);
  const unsigned short* Wsel = Wt + (isQ ? 0 : 262144);

  f32x4 acc[2][4];
  #pragma unroll
  for (int m = 0; m < 2; ++m)
    #pragma unroll
    for (int n = 0; n < 4; ++n) acc[m][n] = (f32x4)0.f;

  const int lr = l & 15, lk = l >> 4;

  for (int k0 = 0; k0 < Hn; k0 += 64) {
    float4 afr[4];
    ushort4 br[4][2];
    #pragma unroll
    for (int i = 0; i < 4; ++i) {          // A: 64r x 64k f32
      int g = t + 256 * i, r = g >> 4, c4 = g & 15;
      afr[i] = *(const float4*)(Asrc + (size_t)(rowBase + r) * Dn + k0 + c4 * 4);
    }
    #pragma unroll
    for (int i = 0; i < 4; ++i) {          // W: 128n x 64k bf16
      int g = t + 256 * i, r = g >> 3, c = g & 7;
      const unsigned short* p = Wsel + (size_t)(n0 + r) * Hn + k0 + c * 8;
      br[i][0] = *(const ushort4*)p; br[i][1] = *(const ushort4*)(p + 4);
    }
    __syncthreads();
    #pragma unroll
    for (int i = 0; i < 4; ++i) {
      int g = t + 256 * i, r = g >> 4, c4 = g & 15;
      ushort4 o = {f2bf(afr[i].x), f2bf(afr[i].y), f2bf(afr[i].z), f2bf(afr[i].w)};
      *(ushort4*)&Al[r][c4 * 4] = o;
    }
    #pragma unroll
    for (int i = 0; i < 4; ++i) {
      int g = t + 256 * i, r = g >> 3, c = g & 7;
      *(ushort4*)&Bl[r][c * 8] = br[i][0]; *(ushort4*)&Bl[r][c * 8 + 4] = br[i][1];
    }
    __syncthreads();
    #pragma unroll
    for (int ks = 0; ks < 2; ++ks) {
      s16x8 af[2], bf_[4];
      #pragma unroll
      for (int m = 0; m < 2; ++m)
        af[m] = *(const s16x8*)&Al[wm * 32 + m * 16 + lr][ks * 32 + lk * 8];
      #pragma unroll
      for (int n = 0; n < 4; ++n)
        bf_[n] = *(const s16x8*)&Bl[wn * 64 + n * 16 + lr][ks * 32 + lk * 8];
      #pragma unroll
      for (int m = 0; m < 2; ++m)
        #pragma unroll
        for (int n = 0; n < 4; ++n)
          acc[m][n] = __builtin_amdgcn_mfma_f32_16x16x32_bf16(af[m], bf_[n], acc[m][n], 0, 0, 0);
    }
    __syncthreads();
  }

  if (isQ) {
    #pragma unroll
    for (int m = 0; m < 2; ++m)
      #pragma unroll
      for (int n = 0; n < 4; ++n)
        #pragma unroll
        for (int r = 0; r < 4; ++r) {
          int row = R0 + wm * 32 + m * 16 + lk * 4 + r;
          int col = n0 + wn * 64 + n * 16 + lr;      // h
          float a = acc[m][n][r];
          float F  = exp2_hw(-PSCALE * a);           // e^{-2q}
          float WF = -2.f * wv[col] * F;
          float2 o = {WF, F};
          *(float2*)(QW + ((size_t)row * Hn + col) * 2) = o;
        }
  } else {
    const int krow0 = R0 - 2048;             // 0..1984, step 64
    const int bb = krow0 >> 7, kb = krow0 & 127;    // batch, k base (0|64)
    const int hl = t >> 2, kq = (t & 3) * 16;
    #pragma unroll
    for (int hc = 0; hc < 2; ++hc) {         // 64-h chunks; wave wn==hc writes
      __syncthreads();
      if (wn == hc) {
        #pragma unroll
        for (int m = 0; m < 2; ++m)
          #pragma unroll
          for (int n = 0; n < 4; ++n)
            #pragma unroll
            for (int r = 0; r < 4; ++r) {
              int row_l = wm * 32 + m * 16 + lk * 4 + r;   // k local 0..63
              int h_l = n * 16 + lr;                        // h local 0..63
              Tep[h_l][row_l] = exp2_hw(PSCALE * acc[m][n][r]);
            }
      }
      __syncthreads();
      float* dst = Ekq + (size_t)bb * 65536 + (size_t)(n0 + hc * 64 + hl) * 128 + kb + kq;
      #pragma unroll
      for (int j = 0; j < 4; ++j)
        *(float4*)(dst + j * 4) = *(const float4*)&Tep[hl][kq + j * 4];
    }
  }
}

// ---------- K3: score partials — Ek in LDS (32KB), QW via global broadcast ----------
// Block = 256 thr (4 waves), owns (b, hs 64h-chunk, 32 q, 128 k). 512 blocks.
// LDS 32.8KB -> 2+ blocks/CU resident (was 49.6KB -> ~1.3).
__global__ __launch_bounds__(256) void score_kernel(
    const float* __restrict__ QW, const float* __restrict__ Ekq,
    float* __restrict__ Sp)
{
  __shared__ float EkL[8192];              // [64 h][128 k] = 32KB
  const int id = blockIdx.x;
  const int g = id & 127, qt = id >> 7;
  const int b = g >> 3, hs = g & 7;
  const int t = threadIdx.x, w = t >> 6, l = t & 63;
  const int qp = w * 8 + ((l >> 4) << 1);
  const int ka = (l & 15) * 4;
  const int h0 = hs * 64;

  {
    const float4* esrc = (const float4*)(Ekq + (size_t)b * 65536 + (size_t)hs * 8192);
    float4 er[8];
    #pragma unroll
    for (int i = 0; i < 8; ++i) er[i] = esrc[t + 256 * i];
    float4* edst = (float4*)EkL;
    #pragma unroll
    for (int i = 0; i < 8; ++i) edst[t + 256 * i] = er[i];
  }
  __syncthreads();

  const float* qwp0 = QW + ((size_t)(b * Qn + qt * 32 + qp) * Hn + h0) * 2;
  const float* qwp1 = qwp0 + 2 * Hn;       // next q row

  float acc0[8], acc1[8];
  #pragma unroll
  for (int j = 0; j < 8; ++j) { acc0[j] = 0.f; acc1[j] = 0.f; }

  float4 nq0 = *(const float4*)(qwp0);
  float4 nq1 = *(const float4*)(qwp1);

  #pragma unroll 4
  for (int hb = 0; hb < 32; ++hb) {
    const float4 qv0 = nq0, qv1 = nq1;
    if (hb < 31) {
      nq0 = *(const float4*)(qwp0 + 4 * (hb + 1));
      nq1 = *(const float4*)(qwp1 + 4 * (hb + 1));
    }
    const float* ekp = EkL + hb * 256;
    float4 ea0 = *(const float4*)(ekp + ka);
    float4 ea1 = *(const float4*)(ekp + 64 + ka);
    float4 eb0 = *(const float4*)(ekp + 128 + ka);
    float4 eb1 = *(const float4*)(ekp + 192 + ka);
    {
      const float WF0 = qv0.x, F0 = qv0.y, WF1 = qv0.z, F1 = qv0.w;
      float d0, d1, num;
      d0 = F0 + ea0.x; d1 = F1 + eb0.x;
      num = __builtin_fmaf(WF0, d1, WF1 * d0);
      acc0[0] = __builtin_fmaf(num, rcp_hw(d0 * d1), acc0[0]);
      d0 = F0 + ea0.y; d1 = F1 + eb0.y;
      num = __builtin_fmaf(WF0, d1, WF1 * d0);
      acc0[1] = __builtin_fmaf(num, rcp_hw(d0 * d1), acc0[1]);
      d0 = F0 + ea0.z; d1 = F1 + eb0.z;
      num = __builtin_fmaf(WF0, d1, WF1 * d0);
      acc0[2] = __builtin_fmaf(num, rcp_hw(d0 * d1), acc0[2]);
      d0 = F0 + ea0.w; d1 = F1 + eb0.w;
      num = __builtin_fmaf(WF0, d1, WF1 * d0);
      acc0[3] = __builtin_fmaf(num, rcp_hw(d0 * d1), acc0[3]);
      d0 = F0 + ea1.x; d1 = F1 + eb1.x;
      num = __builtin_fmaf(WF0, d1, WF1 * d0);
      acc0[4] = __builtin_fmaf(num, rcp_hw(d0 * d1), acc0[4]);
      d0 = F0 + ea1.y; d1 = F1 + eb1.y;
      num = __builtin_fmaf(WF0, d1, WF1 * d0);
      acc0[5] = __builtin_fmaf(num, rcp_hw(d0 * d1), acc0[5]);
      d0 = F0 + ea1.z; d1 = F1 + eb1.z;
      num = __builtin_fmaf(WF0, d1, WF1 * d0);
      acc0[6] = __builtin_fmaf(num, rcp_hw(d0 * d1), acc0[6]);
      d0 = F0 + ea1.w; d1 = F1 + eb1.w;
      num = __builtin_fmaf(WF0, d1, WF1 * d0);
      acc0[7] = __builtin_fmaf(num, rcp_hw(d0 * d1), acc0[7]);
    }
    {
      const float WF0 = qv1.x, F0 = qv1.y, WF1 = qv1.z, F1 = qv1.w;
      float d0, d1, num;
      d0 = F0 + ea0.x; d1 = F1 + eb0.x;
      num = __builtin_fmaf(WF0, d1, WF1 * d0);
      acc1[0] = __builtin_fmaf(num, rcp_hw(d0 * d1), acc1[0]);
      d0 = F0 + ea0.y; d1 = F1 + eb0.y;
      num = __builtin_fmaf(WF0, d1, WF1 * d0);
      acc1[1] = __builtin_fmaf(num, rcp_hw(d0 * d1), acc1[1]);
      d0 = F0 + ea0.z; d1 = F1 + eb0.z;
      num = __builtin_fmaf(WF0, d1, WF1 * d0);
      acc1[2] = __builtin_fmaf(num, rcp_hw(d0 * d1), acc1[2]);
      d0 = F0 + ea0.w; d1 = F1 + eb0.w;
      num = __builtin_fmaf(WF0, d1, WF1 * d0);
      acc1[3] = __builtin_fmaf(num, rcp_hw(d0 * d1), acc1[3]);
      d0 = F0 + ea1.x; d1 = F1 + eb1.x;
      num = __builtin_fmaf(WF0, d1, WF1 * d0);
      acc1[4] = __builtin_fmaf(num, rcp_hw(d0 * d1), acc1[4]);
      d0 = F0 + ea1.y; d1 = F1 + eb1.y;
      num = __builtin_fmaf(WF0, d1, WF1 * d0);
      acc1[5] = __builtin_fmaf(num, rcp_hw(d0 * d1), acc1[5]);
      d0 = F0 + ea1.z; d1 = F1 + eb1.z;
      num = __builtin_fmaf(WF0, d1, WF1 * d0);
      acc1[6] = __builtin_fmaf(num, rcp_hw(d0 * d1), acc1[6]);
      d0 = F0 + ea1.w; d1 = F1 + eb1.w;
      num = __builtin_fmaf(WF0, d1, WF1 * d0);
      acc1[7] = __builtin_fmaf(num, rcp_hw(d0 * d1), acc1[7]);
    }
  }

  const int q = qt * 32 + qp;
  size_t sb = (((size_t)hs * Bn + b) * Qn + q) * Kn;
  *(float4*)(Sp + sb + ka)            = (float4){acc0[0], acc0[1], acc0[2], acc0[3]};
  *(float4*)(Sp + sb + 64 + ka)       = (float4){acc0[4], acc0[5], acc0[6], acc0[7]};
  *(float4*)(Sp + sb + Kn + ka)       = (float4){acc1[0], acc1[1], acc1[2], acc1[3]};
  *(float4*)(Sp + sb + Kn + 64 + ka)  = (float4){acc1[4], acc1[5], acc1[6], acc1[7]};
}

// ---------- K4: fused softmax + AV, grid (8qt x 4dt, 16b) = 512 blocks ----------
// Phase A: sum 8 Sp partials for 16 q, masked softmax -> AtL (LDS bf16).
// Phase B: out[b][16q][dt*128..+128] via MFMA; V staged k-pair-packed u32.
__global__ __launch_bounds__(256) void softmax_av(
    const float* __restrict__ Sp, const int* __restrict__ valid_lens,
    const float* __restrict__ values, float* __restrict__ out)
{
  __shared__ unsigned short AtL[16][136];  // 16 q x 128 k bf16
  __shared__ unsigned int VLu[128][36];    // [d 128][k2 32] u32 = {bf16 k, k+1}
  const int t = threadIdx.x, w = t >> 6, l = t & 63;
  const int b = blockIdx.y;
  const int qt = blockIdx.x & 7;           // 16-q tile
  const int dt = blockIdx.x >> 3;          // 0..3 (128-d tile)
  const int lr = l & 15, lk = l >> 4;

  // ---- Phase A: softmax (thread: q = t>>4, 8 k at (t&15)*8) ----
  {
    const int q_l = t >> 4, k8 = (t & 15) * 8;
    const size_t base = ((size_t)(b * Qn) + qt * 16 + q_l) * Kn + k8;
    float s[8] = {0.f, 0.f, 0.f, 0.f, 0.f, 0.f, 0.f, 0.f};
    #pragma unroll
    for (int p = 0; p < 8; ++p) {
      float4 a0 = *(const float4*)(Sp + base + (size_t)p * 262144);
      float4 a1 = *(const float4*)(Sp + base + (size_t)p * 262144 + 4);
      s[0] += a0.x; s[1] += a0.y; s[2] += a0.z; s[3] += a0.w;
      s[4] += a1.x; s[5] += a1.y; s[6] += a1.z; s[7] += a1.w;
    }
    const int vlen = valid_lens[b];
    bool ok[8];
    float m = NEGV;
    #pragma unroll
    for (int j = 0; j < 8; ++j) {
      ok[j] = (k8 + j) < vlen;
      if (ok[j]) m = fmaxf(m, s[j]);
    }
    #pragma unroll
    for (int xm = 8; xm >= 1; xm >>= 1) m = fmaxf(m, __shfl_xor(m, xm));
    float e[8], sum = 0.f;
    #pragma unroll
    for (int j = 0; j < 8; ++j) {
      e[j] = ok[j] ? exp2_hw((s[j] - m) * 1.44269504f) : 0.f;
      sum += e[j];
    }
    #pragma unroll
    for (int xm = 8; xm >= 1; xm >>= 1) sum += __shfl_xor(sum, xm);
    float inv = rcp_hw(sum);
    ushort4 o0 = {f2bf(e[0] * inv), f2bf(e[1] * inv), f2bf(e[2] * inv), f2bf(e[3] * inv)};
    ushort4 o1 = {f2bf(e[4] * inv), f2bf(e[5] * inv), f2bf(e[6] * inv), f2bf(e[7] * inv)};
    *(ushort4*)&AtL[q_l][k8] = o0;
    *(ushort4*)&AtL[q_l][k8 + 4] = o1;
  }
  __syncthreads();

  // ---- Phase B: AV for fixed dt. Wave w owns d cols [w*32, w*32+32) ----
  const int kread = t & 15, dread = (t >> 4) & 15;
  f32x4 acc[2];
  acc[0] = (f32x4)0.f; acc[1] = (f32x4)0.f;
  #pragma unroll
  for (int k0 = 0; k0 < Kn; k0 += 64) {
    if (k0) __syncthreads();               // prev MFMA readers done with VLu
    #pragma unroll
    for (int j = 0; j < 4; ++j) {
      int k2 = kread + 16 * (j & 1);       // 0..31 (k pair index)
      int d4 = dread + 16 * (j >> 1);      // 0..31 (d quad)
      const float* vp = values + ((size_t)(b * Kn) + k0 + 2 * k2) * Dn + dt * 128 + d4 * 4;
      float4 v0 = *(const float4*)(vp);
      float4 v1 = *(const float4*)(vp + Dn);
      VLu[d4 * 4 + 0][k2] = pack2bf(v0.x, v1.x);
      VLu[d4 * 4 + 1][k2] = pack2bf(v0.y, v1.y);
      VLu[d4 * 4 + 2][k2] = pack2bf(v0.z, v1.z);
      VLu[d4 * 4 + 3][k2] = pack2bf(v0.w, v1.w);
    }
    __syncthreads();
    #pragma unroll
    for (int ks = 0; ks < 2; ++ks) {
      s16x8 af = *(const s16x8*)&AtL[lr][k0 + ks * 32 + lk * 8];
      #pragma unroll
      for (int nn = 0; nn < 2; ++nn) {
        s16x8 bv = *(const s16x8*)&VLu[w * 32 + nn * 16 + lr][ks * 16 + lk * 4];
        acc[nn] = __builtin_amdgcn_mfma_f32_16x16x32_bf16(af, bv, acc[nn], 0, 0, 0);
      }
    }
  }
  #pragma unroll
  for (int nn = 0; nn < 2; ++nn)
    #pragma unroll
    for (int r = 0; r < 4; ++r) {
      int q = qt * 16 + lk * 4 + r;
      int d = dt * 128 + w * 32 + nn * 16 + lr;
      out[((size_t)(b * Qn) + q) * Dn + d] = acc[nn][r];
    }
}

extern "C" void kernel_launch(void* const* d_in, const int* in_sizes, int n_in,
                              void* d_out, int out_size, void* d_ws, size_t ws_size,
                              hipStream_t stream) {
  const float* queries    = (const float*)d_in[0];
  const float* keys       = (const float*)d_in[1];
  const float* values     = (const float*)d_in[2];
  const int*   valid_lens = (const int*)d_in[3];
  const float* Wq         = (const float*)d_in[4];
  const float* Wk         = (const float*)d_in[5];
  const float* wv         = (const float*)d_in[6];
  float* out = (float*)d_out;

  unsigned short* Wt  = (unsigned short*)d_ws;     // 2*512*512 bf16      (1MB)
  float*          QW  = (float*)(Wt + 524288);     // 2048*512*2 f32      (8MB)
  float*          Ekq = QW + 2097152;              // 16*512*128 f32      (4MB)
  float*          Sp  = Ekq + 1048576;             // 8*16*128*128 f32    (8MB)

  convert_w<<<128, 256, 0, stream>>>(Wq, Wk, Wt);
  proj_mfma<<<dim3(64, 4), 256, 0, stream>>>(queries, keys, Wt, wv, QW, Ekq);
  score_kernel<<<512, 256, 0, stream>>>(QW, Ekq, Sp);
  softmax_av<<<dim3(32, 16), 256, 0, stream>>>(Sp, valid_lens, values, out);
}